// Round 7
// baseline (1522.073 us; speedup 1.0000x reference)
//
#include <hip/hip_runtime.h>
#include <cstdint>
#include <cmath>

#define DI __device__ __forceinline__

constexpr int BB = 16;      // batch
constexpr int NN = 1024;    // points
constexpr int KK = 20;      // neighbors
constexpr int NPT = BB*NN;  // total points 16384
constexpr float EPSF = 1e-5f;
constexpr float NEGINF = -3.0e38f;

DI float lrelu(float x){ return x >= 0.f ? x : 0.2f * x; }
DI float dot4(const float4 a, const float4 b){ return a.x*b.x + a.y*b.y + a.z*b.z + a.w*b.w; }
DI unsigned short f2bf(float x){            // round-to-nearest-even bf16
    uint32_t u = __float_as_uint(x);
    uint32_t r = (u + 0x7fffu + ((u >> 16) & 1u)) >> 16;
    return (unsigned short)r;
}

typedef __attribute__((ext_vector_type(8))) short short8v;  // bf16x8 MFMA fragment
typedef __attribute__((ext_vector_type(4))) float f32x4;

// ---------------------------------------------------------------- transpose x [B,3,N] -> xt0 [B,N,3]
__global__ void k_transpose(const float* __restrict__ x, float* __restrict__ xt)
{
    int i = blockIdx.x * 256 + threadIdx.x;
    if (i >= NPT) return;
    int b = i >> 10, n = i & 1023;
    #pragma unroll
    for (int c = 0; c < 3; ++c) xt[i*3 + c] = x[(b*3 + c)*NN + n];
}

// ---------------------------------------------------------------- squared norms per point
__global__ void k_sqnorm(const float* __restrict__ src, int stride, int C, float* __restrict__ xx)
{
    int i = blockIdx.x * 256 + threadIdx.x;
    if (i >= NPT) return;
    const float* r = src + (size_t)i * stride;
    float s = 0.f;
    for (int c = 0; c < C; ++c){ float v = r[c]; s += v * v; }
    xx[i] = s;
}

// ---------------------------------------------------------------- kNN
// Block = 512 threads (8 waves), 32 queries (wave -> 4 queries), grid 512
// (2 blocks/CU). Distance phase: chunk over dims (8/chunk); ALL 1024
// candidates' chunk staged in LDS (48KB, 48B row stride -> conflict-free
// b128: bank = 3*lane+s mod 8, gcd(3,8)=1). Queries are wave-uniform scalar
// loads (off the LDS pipe). Accumulate into val[4][16]. Selection: per-lane
// bitonic sort + 21-round tournament for T=21st-largest + set emission.
template<int C>
__global__ __launch_bounds__(512, 4) void k_knn(const float* __restrict__ src, int stride,
                                                const float* __restrict__ xx,
                                                int* __restrict__ idxo)
{
    constexpr bool SMALL = (C == 3);
    constexpr int NCH = SMALL ? 1 : (C / 8);       // dim-chunks
    constexpr int RS  = SMALL ? 4 : 12;            // tile row stride (floats)
    __shared__ float tile[1024 * RS];              // 16KB small / 48KB big

    const int tid  = threadIdx.x;
    const int lane = tid & 63;
    const int wv   = __builtin_amdgcn_readfirstlane(tid >> 6);  // 0..7 uniform
    const int b    = blockIdx.x >> 5;
    const int q0   = (blockIdx.x & 31) << 5;       // 32 queries per block
    const int qbase = b*NN + q0 + (wv << 2);       // wave's first query (uniform)

    float val[4][16];
    #pragma unroll
    for (int q = 0; q < 4; ++q)
        #pragma unroll
        for (int j = 0; j < 16; ++j) val[q][j] = 0.f;

    for (int ch = 0; ch < NCH; ++ch){
        const int c0 = ch << 3;
        __syncthreads();                           // previous chunk fully consumed
        // ---- stage all 1024 candidates' chunk ----
        if constexpr (SMALL){
            #pragma unroll
            for (int r = 0; r < 2; ++r){
                int c = tid*2 + r;
                const float* sp = src + (size_t)(b*NN + c)*3;
                float4 v; v.x = sp[0]; v.y = sp[1]; v.z = sp[2]; v.w = 0.f;
                *(float4*)(tile + c*4) = v;
            }
        } else {
            #pragma unroll
            for (int k = 0; k < 4; ++k){
                int id = tid + k*512;              // 0..2047
                int c = id >> 1, part = id & 1;
                float4 v = *(const float4*)(src + (size_t)(b*NN + c)*stride + c0 + part*4);
                *(float4*)(tile + c*12 + part*4) = v;
            }
        }
        // ---- wave-uniform query chunk (scalar loads) ----
        float4 qa[4], qb4[4];
        if constexpr (SMALL){
            #pragma unroll
            for (int q = 0; q < 4; ++q){
                const float* qp = src + (size_t)(qbase + q)*3;
                qa[q].x = qp[0]; qa[q].y = qp[1]; qa[q].z = qp[2]; qa[q].w = 0.f;
            }
        } else {
            #pragma unroll
            for (int q = 0; q < 4; ++q){
                const float* qp = src + (size_t)(qbase + q)*stride + c0;
                qa[q]  = *(const float4*)(qp);
                qb4[q] = *(const float4*)(qp + 4);
            }
        }
        __syncthreads();

        // ---- accumulate inner products: lane owns candidates j*64+lane ----
        #pragma unroll
        for (int j = 0; j < 16; ++j){
            if constexpr (SMALL){
                float4 cf = *(const float4*)(tile + (size_t)(j*64 + lane)*4);
                #pragma unroll
                for (int q = 0; q < 4; ++q)
                    val[q][j] += qa[q].x*cf.x + qa[q].y*cf.y + qa[q].z*cf.z;
            } else {
                const float* cp = tile + (size_t)(j*64 + lane)*12;
                float4 cf0 = *(const float4*)(cp);
                float4 cf1 = *(const float4*)(cp + 4);
                #pragma unroll
                for (int q = 0; q < 4; ++q)
                    val[q][j] += dot4(qa[q], cf0) + dot4(qb4[q], cf1);
            }
        }
    }

    // ---- finalize: neg squared distance ----
    float xxq[4];
    #pragma unroll
    for (int q = 0; q < 4; ++q) xxq[q] = xx[qbase + q];
    #pragma unroll
    for (int j = 0; j < 16; ++j){
        float xm = xx[b*NN + j*64 + lane];
        #pragma unroll
        for (int q = 0; q < 4; ++q)
            val[q][j] = 2.f*val[q][j] - xxq[q] - xm;
    }

    // ---- selection per query ----
    #pragma unroll
    for (int q = 0; q < 4; ++q){
        const int orow = (qbase + q) * KK;

        // copy + bitonic sort descending (values only, static indices)
        float s[16];
        #pragma unroll
        for (int j = 0; j < 16; ++j) s[j] = val[q][j];
        #pragma unroll
        for (int k = 2; k <= 16; k <<= 1){
            #pragma unroll
            for (int jj = k >> 1; jj > 0; jj >>= 1){
                #pragma unroll
                for (int i = 0; i < 16; ++i){
                    int l = i ^ jj;
                    if (l > i){
                        float a = s[i], c = s[l];
                        float mx = fmaxf(a, c), mn = fminf(a, c);
                        bool up = ((i & k) == 0);
                        s[i] = up ? mx : mn;
                        s[l] = up ? mn : mx;
                    }
                }
            }
        }

        // 21 tournament rounds over lane heads -> T = 21st-largest
        float T = NEGINF;
        for (int it = 0; it < 21; ++it){
            float m = s[0];
            #pragma unroll
            for (int d = 1; d < 64; d <<= 1) m = fmaxf(m, __shfl_xor(m, d));
            T = m;
            unsigned long long mk = __ballot(s[0] == m);
            int wl = __ffsll(mk) - 1;
            bool adv = (lane == wl);
            #pragma unroll
            for (int j = 0; j < 15; ++j) s[j] = adv ? s[j+1] : s[j];
            s[15] = adv ? NEGINF : s[15];
        }

        // emit {val > T} (order irrelevant downstream), fill ==T by lowest index
        int cnt = 0;
        #pragma unroll
        for (int j = 0; j < 16; ++j) cnt += (val[q][j] > T) ? 1 : 0;
        int off = cnt;
        #pragma unroll
        for (int d = 1; d < 64; d <<= 1){
            int tt = __shfl_up(off, d);
            if (lane >= d) off += tt;
        }
        int total = __shfl(off, 63);
        int pos = orow + off - cnt;
        #pragma unroll
        for (int j = 0; j < 16; ++j){
            if (val[q][j] > T){ idxo[pos] = j*64 + lane; ++pos; }
        }
        if (total < KK){
            int rem = KK - total;
            int prior = 0;
            #pragma unroll
            for (int j = 0; j < 16; ++j){
                unsigned long long mk = __ballot(val[q][j] == T);
                int below = __popcll(mk & ((1ull << lane) - 1ull));
                if ((val[q][j] == T) && (prior + below < rem))
                    idxo[orow + total + prior + below] = j*64 + lane;
                prior += __popcll(mk);
            }
        }
    }
}

// ---------------------------------------------------------------- weight prep: W' = [Wj ; Wi-Wj]
__global__ void k_wprep(const float* __restrict__ w, int O, int C, float* __restrict__ wp)
{
    int i = blockIdx.x*256 + threadIdx.x;
    if (i >= O*C) return;
    int o = i / C, c = i % C;
    float a = w[o*2*C + c];
    float bq = w[o*2*C + C + c];
    wp[o*C + c]       = a;
    wp[(O + o)*C + c] = bq - a;
}

// ---------------------------------------------------------------- u/v GEMM (fp32: feeds next kNN, must stay exact)
template<int K, int M2, int O>
__global__ __launch_bounds__(256) void k_uvgemm(const float* __restrict__ srcp,
    const float* __restrict__ wp,
    const float* __restrict__ g, const float* __restrict__ bp,
    const float* __restrict__ mp, const float* __restrict__ vp,
    float* __restrict__ ub, float* __restrict__ xcv)
{
    constexpr int LD = 136;
    __shared__ float wl[16*LD];
    __shared__ float xl[16*LD];
    const int tid = threadIdx.x;
    const int nt = blockIdx.x & 127;
    const int mt = blockIdx.x >> 7;
    const int to = tid >> 4, tn = tid & 15;

    float acc[8][8];
    #pragma unroll
    for (int i = 0; i < 8; ++i)
        #pragma unroll
        for (int j = 0; j < 8; ++j) acc[i][j] = 0.f;

    for (int c0 = 0; c0 < K; c0 += 16){
        __syncthreads();
        #pragma unroll
        for (int p = 0; p < 2; ++p){
            int fi = tid + (p << 8);
            int row = fi >> 2, cq = (fi & 3) << 2;
            float4 wv = *(const float4*)(wp + (size_t)(mt*128 + row)*K + c0 + cq);
            wl[(cq+0)*LD + row] = wv.x;
            wl[(cq+1)*LD + row] = wv.y;
            wl[(cq+2)*LD + row] = wv.z;
            wl[(cq+3)*LD + row] = wv.w;
            float4 xv = *(const float4*)(srcp + (size_t)(nt*128 + row)*512 + c0 + cq);
            xl[(cq+0)*LD + row] = xv.x;
            xl[(cq+1)*LD + row] = xv.y;
            xl[(cq+2)*LD + row] = xv.z;
            xl[(cq+3)*LD + row] = xv.w;
        }
        __syncthreads();
        #pragma unroll
        for (int cc = 0; cc < 16; ++cc){
            float4 a0 = *(const float4*)(wl + cc*LD + to*8);
            float4 a1 = *(const float4*)(wl + cc*LD + to*8 + 4);
            float4 b0 = *(const float4*)(xl + cc*LD + tn*8);
            float4 b1 = *(const float4*)(xl + cc*LD + tn*8 + 4);
            float av[8] = {a0.x,a0.y,a0.z,a0.w,a1.x,a1.y,a1.z,a1.w};
            float bv[8] = {b0.x,b0.y,b0.z,b0.w,b1.x,b1.y,b1.z,b1.w};
            #pragma unroll
            for (int i = 0; i < 8; ++i)
                #pragma unroll
                for (int j = 0; j < 8; ++j) acc[i][j] += av[i]*bv[j];
        }
    }

    const int mbase = mt*128 + to*8;
    const bool isu = mbase < O;
    float mult[8], add[8];
    #pragma unroll
    for (int i = 0; i < 8; ++i){
        int m = mbase + i;
        if (isu){
            float s = g[m] / sqrtf(vp[m] + EPSF);
            mult[i] = (s >= 0.f) ? 1.f : -1.f;
            add[i]  = 0.f;
        } else {
            int o = m - O;
            float s = g[o] / sqrtf(vp[o] + EPSF);
            mult[i] = s;
            add[i]  = bp[o] - mp[o]*s;
        }
    }
    #pragma unroll
    for (int j = 0; j < 8; ++j){
        int pt = nt*128 + tn*8 + j;
        float4 v0, v1;
        v0.x = fmaf(mult[0], acc[0][j], add[0]);
        v0.y = fmaf(mult[1], acc[1][j], add[1]);
        v0.z = fmaf(mult[2], acc[2][j], add[2]);
        v0.w = fmaf(mult[3], acc[3][j], add[3]);
        v1.x = fmaf(mult[4], acc[4][j], add[4]);
        v1.y = fmaf(mult[5], acc[5][j], add[5]);
        v1.z = fmaf(mult[6], acc[6][j], add[6]);
        v1.w = fmaf(mult[7], acc[7][j], add[7]);
        if (isu){
            float* d = ub + (size_t)pt*O + mbase;
            *(float4*)(d)     = v0;
            *(float4*)(d + 4) = v1;
        } else {
            float* d = xcv + (size_t)pt*512 + (mbase - O);
            *(float4*)(d)     = v0;
            *(float4*)(d + 4) = v1;
        }
    }
}

// ---------------------------------------------------------------- layer-1 u/v (C=3) direct
__global__ __launch_bounds__(256) void k_uv3(const float* __restrict__ xt,
    const float* __restrict__ wp,
    const float* __restrict__ g, const float* __restrict__ bp,
    const float* __restrict__ mp, const float* __restrict__ vp,
    float* __restrict__ ub, float* __restrict__ xcv)
{
    __shared__ float wpl[128*3];
    __shared__ float mult[128], add[128];
    const int tid = threadIdx.x;
    if (tid < 128){
        int m = tid;
        if (m < 64){
            float s = g[m] / sqrtf(vp[m] + EPSF);
            mult[m] = (s >= 0.f) ? 1.f : -1.f;
            add[m]  = 0.f;
        } else {
            int o = m - 64;
            float s = g[o] / sqrtf(vp[o] + EPSF);
            mult[m] = s;
            add[m]  = bp[o] - mp[o]*s;
        }
    }
    for (int i = tid; i < 128*3; i += 256) wpl[i] = wp[i];
    __syncthreads();

    const int ptl = tid >> 5, mg = tid & 31;
    const int m0 = mg * 4;
    const int pt = blockIdx.x*8 + ptl;
    float x0 = xt[pt*3+0], x1 = xt[pt*3+1], x2 = xt[pt*3+2];
    float4 v4;
    float tmp[4];
    #pragma unroll
    for (int r = 0; r < 4; ++r){
        int m = m0 + r;
        float a = wpl[m*3+0]*x0 + wpl[m*3+1]*x1 + wpl[m*3+2]*x2;
        tmp[r] = fmaf(mult[m], a, add[m]);
    }
    v4.x = tmp[0]; v4.y = tmp[1]; v4.z = tmp[2]; v4.w = tmp[3];
    if (m0 < 64) *(float4*)(ub + (size_t)pt*64 + m0) = v4;
    else         *(float4*)(xcv + (size_t)pt*512 + (m0 - 64)) = v4;
}

// ---------------------------------------------------------------- combine: out = lrelu(|s| * max_k u'[j_k] + v')
template<int O>
__global__ __launch_bounds__(256) void k_edgemax(const float* __restrict__ ub,
    const int* __restrict__ idxg,
    const float* __restrict__ g, const float* __restrict__ vp,
    float* __restrict__ xcv)
{
    constexpr int TPP = O / 4;
    constexpr int PPB = 256 / TPP;
    const int tid = threadIdx.x;
    const int pt  = blockIdx.x*PPB + tid / TPP;
    const int oq  = (tid % TPP) * 4;
    const int bb  = pt & ~(NN-1);

    int nb[KK];
    #pragma unroll
    for (int k = 0; k < KK; ++k) nb[k] = idxg[pt*KK + k];

    float4 mx = *(const float4*)(ub + (size_t)(bb + nb[0])*O + oq);
    #pragma unroll
    for (int k = 1; k < KK; ++k){
        float4 u = *(const float4*)(ub + (size_t)(bb + nb[k])*O + oq);
        mx.x = fmaxf(mx.x, u.x); mx.y = fmaxf(mx.y, u.y);
        mx.z = fmaxf(mx.z, u.z); mx.w = fmaxf(mx.w, u.w);
    }
    float4 gv = *(const float4*)(g + oq);
    float4 vv = *(const float4*)(vp + oq);
    float4 as;
    as.x = fabsf(gv.x / sqrtf(vv.x + EPSF));
    as.y = fabsf(gv.y / sqrtf(vv.y + EPSF));
    as.z = fabsf(gv.z / sqrtf(vv.z + EPSF));
    as.w = fabsf(gv.w / sqrtf(vv.w + EPSF));
    float* d = xcv + (size_t)pt*512 + oq;
    float4 vr = *(const float4*)(d);
    float4 y;
    y.x = lrelu(fmaf(as.x, mx.x, vr.x));
    y.y = lrelu(fmaf(as.y, mx.y, vr.y));
    y.z = lrelu(fmaf(as.z, mx.z, vr.z));
    y.w = lrelu(fmaf(as.w, mx.w, vr.w));
    *(float4*)(d) = y;
}

// ---------------------------------------------------------------- fp32 -> bf16 cast (8 elems/thread)
__global__ void k_castbf(const float* __restrict__ s, unsigned short* __restrict__ d, int n8)
{
    int i = blockIdx.x*256 + threadIdx.x;
    if (i >= n8) return;
    const float4* sp = (const float4*)s + (size_t)i*2;
    float4 a = sp[0], b = sp[1];
    union { unsigned short u[8]; uint4 v; } o;
    o.u[0] = f2bf(a.x); o.u[1] = f2bf(a.y); o.u[2] = f2bf(a.z); o.u[3] = f2bf(a.w);
    o.u[4] = f2bf(b.x); o.u[5] = f2bf(b.y); o.u[6] = f2bf(b.z); o.u[7] = f2bf(b.w);
    *((uint4*)d + i) = o.v;
}

// ---------------------------------------------------------------- conv5 bf16 MFMA GEMM + BN + LReLU + pool partials
__global__ __launch_bounds__(256) void k_conv5mfma(const unsigned short* __restrict__ xcb,
    const unsigned short* __restrict__ w5b,
    const float* __restrict__ g, const float* __restrict__ bp,
    const float* __restrict__ mp, const float* __restrict__ vp,
    float* __restrict__ pmax, float* __restrict__ psum)
{
    __shared__ __align__(16) short lA[128*32];
    __shared__ __align__(16) short lB[128*32];
    __shared__ float scl[128], adl[128];
    __shared__ float red[2][128][2];

    const int tid = threadIdx.x;
    const int lane = tid & 63, wave = tid >> 6;
    const int wm = wave >> 1, wn = wave & 1;
    const int b  = blockIdx.x >> 6;
    const int mt = (blockIdx.x >> 3) & 7;
    const int nt = blockIdx.x & 7;

    if (tid < 128){
        int o = mt*128 + tid;
        float s = g[o] / sqrtf(vp[o] + EPSF);
        scl[tid] = s;
        adl[tid] = bp[o] - mp[o]*s;
    }

    f32x4 acc[4][4];
    #pragma unroll
    for (int i = 0; i < 4; ++i)
        #pragma unroll
        for (int j = 0; j < 4; ++j) acc[i][j] = (f32x4){0.f,0.f,0.f,0.f};

    const unsigned short* gA = w5b + (size_t)(mt*128)*512;
    const unsigned short* gB = xcb + (size_t)(b*1024 + nt*128)*512;

    for (int ks = 0; ks < 16; ++ks){
        __syncthreads();
        #pragma unroll
        for (int p = 0; p < 2; ++p){
            int off = p*256 + tid;
            int row = off >> 2;
            int slot = off & 3;
            int ssl = slot ^ (row & 3);
            *(uint4*)(lA + row*32 + ssl*8) = *(const uint4*)(gA + (size_t)row*512 + ks*32 + slot*8);
            *(uint4*)(lB + row*32 + ssl*8) = *(const uint4*)(gB + (size_t)row*512 + ks*32 + slot*8);
        }
        __syncthreads();

        short8v afr[4], bfr[4];
        #pragma unroll
        for (int i = 0; i < 4; ++i){
            int row = wm*64 + i*16 + (lane & 15);
            int sl  = (lane >> 4) ^ (row & 3);
            afr[i] = *(const short8v*)(lA + row*32 + sl*8);
        }
        #pragma unroll
        for (int j = 0; j < 4; ++j){
            int row = wn*64 + j*16 + (lane & 15);
            int sl  = (lane >> 4) ^ (row & 3);
            bfr[j] = *(const short8v*)(lB + row*32 + sl*8);
        }
        #pragma unroll
        for (int i = 0; i < 4; ++i)
            #pragma unroll
            for (int j = 0; j < 4; ++j)
                acc[i][j] = __builtin_amdgcn_mfma_f32_16x16x32_bf16(afr[i], bfr[j], acc[i][j], 0, 0, 0);
    }

    float emx[4][4], esm[4][4];
    #pragma unroll
    for (int i = 0; i < 4; ++i){
        #pragma unroll
        for (int r = 0; r < 4; ++r){
            int m_loc = wm*64 + i*16 + (lane >> 4)*4 + r;
            float s = scl[m_loc], t = adl[m_loc];
            float mx = NEGINF, sm = 0.f;
            #pragma unroll
            for (int j = 0; j < 4; ++j){
                float y = lrelu(fmaf(acc[i][j][r], s, t));
                mx = fmaxf(mx, y); sm += y;
            }
            #pragma unroll
            for (int d = 1; d < 16; d <<= 1){
                mx = fmaxf(mx, __shfl_xor(mx, d));
                sm += __shfl_xor(sm, d);
            }
            emx[i][r] = mx; esm[i][r] = sm;
        }
    }
    if ((lane & 15) == 0){
        #pragma unroll
        for (int i = 0; i < 4; ++i)
            #pragma unroll
            for (int r = 0; r < 4; ++r){
                int m_loc = wm*64 + i*16 + (lane >> 4)*4 + r;
                red[wn][m_loc][0] = emx[i][r];
                red[wn][m_loc][1] = esm[i][r];
            }
    }
    __syncthreads();
    if (tid < 128){
        float mx = fmaxf(red[0][tid][0], red[1][tid][0]);
        float sm = red[0][tid][1] + red[1][tid][1];
        int o = mt*128 + tid;
        pmax[(size_t)(b*NN + o)*8 + nt] = mx;
        psum[(size_t)(b*NN + o)*8 + nt] = sm;
    }
}

__global__ void k_poolfin(const float* __restrict__ pmax, const float* __restrict__ psum,
                          float* __restrict__ p)
{
    int i = blockIdx.x*256 + threadIdx.x;
    if (i >= NPT) return;
    int b = i >> 10, o = i & 1023;
    float mx = NEGINF, sm = 0.f;
    #pragma unroll
    for (int t = 0; t < 8; ++t){ mx = fmaxf(mx, pmax[(size_t)i*8 + t]); sm += psum[(size_t)i*8 + t]; }
    p[b*2048 + o]        = mx;
    p[b*2048 + 1024 + o] = sm * (1.f/1024.f);
}

// ---------------------------------------------------------------- small FC layers
template<int IN, int O, bool HASBN, bool HASBIAS>
__global__ void k_fc(const float* __restrict__ in, const float* __restrict__ W,
                     const float* __restrict__ bias,
                     const float* __restrict__ g, const float* __restrict__ bp,
                     const float* __restrict__ mp, const float* __restrict__ vp,
                     float* __restrict__ out)
{
    int i = blockIdx.x*256 + threadIdx.x;
    if (i >= BB*O) return;
    int b = i / O, o = i % O;
    const float* wr = W  + (size_t)o*IN;
    const float* ir = in + (size_t)b*IN;
    float s = 0.f;
    #pragma unroll 4
    for (int c = 0; c < IN; c += 4){
        float4 a = *(const float4*)(wr + c);
        float4 x = *(const float4*)(ir + c);
        s += dot4(a, x);
    }
    if (HASBIAS) s += bias[o];
    if (HASBN){
        float sc = g[o] / sqrtf(vp[o] + EPSF);
        s = (s - mp[o])*sc + bp[o];
        s = lrelu(s);
    }
    out[(size_t)b*O + o] = s;
}

// ---------------------------------------------------------------- launch
extern "C" void kernel_launch(void* const* d_in, const int* in_sizes, int n_in,
                              void* d_out, int out_size, void* d_ws, size_t ws_size,
                              hipStream_t stream)
{
    (void)in_sizes; (void)n_in; (void)out_size; (void)ws_size;
    const float* x   = (const float*)d_in[0];
    const float* w1  = (const float*)d_in[1];
    const float* w2  = (const float*)d_in[2];
    const float* w3  = (const float*)d_in[3];
    const float* w4  = (const float*)d_in[4];
    const float* w5  = (const float*)d_in[5];
    const float* wl1 = (const float*)d_in[6];
    const float* wl2 = (const float*)d_in[7];
    const float* wl3 = (const float*)d_in[8];
    const float* bl2 = (const float*)d_in[9];
    const float* bl3 = (const float*)d_in[10];
    const float* g1 = (const float*)d_in[11]; const float* b1 = (const float*)d_in[12];
    const float* m1 = (const float*)d_in[13]; const float* v1 = (const float*)d_in[14];
    const float* g2 = (const float*)d_in[15]; const float* b2 = (const float*)d_in[16];
    const float* m2 = (const float*)d_in[17]; const float* v2 = (const float*)d_in[18];
    const float* g3 = (const float*)d_in[19]; const float* b3 = (const float*)d_in[20];
    const float* m3 = (const float*)d_in[21]; const float* v3 = (const float*)d_in[22];
    const float* g4 = (const float*)d_in[23]; const float* b4 = (const float*)d_in[24];
    const float* m4 = (const float*)d_in[25]; const float* v4 = (const float*)d_in[26];
    const float* g5 = (const float*)d_in[27]; const float* b5 = (const float*)d_in[28];
    const float* m5 = (const float*)d_in[29]; const float* v5 = (const float*)d_in[30];
    const float* g6 = (const float*)d_in[31]; const float* b6 = (const float*)d_in[32];
    const float* m6 = (const float*)d_in[33]; const float* v6 = (const float*)d_in[34];
    const float* g7 = (const float*)d_in[35]; const float* b7 = (const float*)d_in[36];
    const float* m7 = (const float*)d_in[37]; const float* v7 = (const float*)d_in[38];

    float* wsf  = (float*)d_ws;
    float* xt0  = wsf;                    // 49152
    float* xc   = xt0 + 49152;            // 8388608
    float* xx   = xc + 8388608;           // 16384
    int*   idx  = (int*)(xx + 16384);     // 327680 ints
    float* pmax = (float*)(idx + 327680); // 131072
    float* psum = pmax + 131072;          // 131072
    float* p    = psum + 131072;          // 32768
    float* h1   = p + 32768;              // 8192
    float* h2   = h1 + 8192;              // 4096
    float* ub   = h2 + 4096;              // 4194304
    float* wp   = ub + 4194304;           // 65536
    unsigned short* xcb = (unsigned short*)ub;   // bf16 alias (ub dead by conv5)
    unsigned short* w5b = (unsigned short*)idx;  // bf16 alias (idx dead by conv5)

    k_transpose<<<64, 256, 0, stream>>>(x, xt0);

    // block 1: C=3 -> O=64 (channels 0..63)
    k_sqnorm<<<64, 256, 0, stream>>>(xt0, 3, 3, xx);
    k_knn<3><<<512, 512, 0, stream>>>(xt0, 3, xx, idx);
    k_wprep<<<1, 256, 0, stream>>>(w1, 64, 3, wp);
    k_uv3<<<2048, 256, 0, stream>>>(xt0, wp, g1, b1, m1, v1, ub, xc);
    k_edgemax<64><<<1024, 256, 0, stream>>>(ub, idx, g1, v1, xc);

    // block 2: C=64 -> O=64 (channels 64..127)
    k_sqnorm<<<64, 256, 0, stream>>>(xc, 512, 64, xx);
    k_knn<64><<<512, 512, 0, stream>>>(xc, 512, xx, idx);
    k_wprep<<<16, 256, 0, stream>>>(w2, 64, 64, wp);
    k_uvgemm<64, 128, 64><<<128, 256, 0, stream>>>(xc, wp, g2, b2, m2, v2, ub, xc + 64);
    k_edgemax<64><<<1024, 256, 0, stream>>>(ub, idx, g2, v2, xc + 64);

    // block 3: C=64 -> O=128 (channels 128..255)
    k_sqnorm<<<64, 256, 0, stream>>>(xc + 64, 512, 64, xx);
    k_knn<64><<<512, 512, 0, stream>>>(xc + 64, 512, xx, idx);
    k_wprep<<<32, 256, 0, stream>>>(w3, 128, 64, wp);
    k_uvgemm<64, 256, 128><<<256, 256, 0, stream>>>(xc + 64, wp, g3, b3, m3, v3, ub, xc + 128);
    k_edgemax<128><<<2048, 256, 0, stream>>>(ub, idx, g3, v3, xc + 128);

    // block 4: C=128 -> O=256 (channels 256..511)
    k_sqnorm<<<64, 256, 0, stream>>>(xc + 128, 512, 128, xx);
    k_knn<128><<<512, 512, 0, stream>>>(xc + 128, 512, xx, idx);
    k_wprep<<<128, 256, 0, stream>>>(w4, 256, 128, wp);
    k_uvgemm<128, 512, 256><<<512, 256, 0, stream>>>(xc + 128, wp, g4, b4, m4, v4, ub, xc + 256);
    k_edgemax<256><<<4096, 256, 0, stream>>>(ub, idx, g4, v4, xc + 256);

    // conv5: cast to bf16 (ub/idx now dead), MFMA GEMM + fused BN/LReLU/pool
    k_castbf<<<4096, 256, 0, stream>>>(xc, xcb, 1048576);
    k_castbf<<<256, 256, 0, stream>>>(w5, w5b, 65536);
    k_conv5mfma<<<1024, 256, 0, stream>>>(xcb, w5b, g5, b5, m5, v5, pmax, psum);
    k_poolfin<<<64, 256, 0, stream>>>(pmax, psum, p);

    // FC head
    k_fc<2048, 512, true,  false><<<32, 256, 0, stream>>>(p,  wl1, nullptr, g6, b6, m6, v6, h1);
    k_fc<512,  256, true,  true ><<<16, 256, 0, stream>>>(h1, wl2, bl2,     g7, b7, m7, v7, h2);
    k_fc<256,  101, false, true ><<<7,  256, 0, stream>>>(h2, wl3, bl3, nullptr, nullptr, nullptr, nullptr, (float*)d_out);
}

// Round 8
// 612.001 us; speedup vs baseline: 2.4870x; 2.4870x over previous
//
#include <hip/hip_runtime.h>
#include <cstdint>
#include <cmath>

#define DI __device__ __forceinline__

constexpr int BB = 16;      // batch
constexpr int NN = 1024;    // points
constexpr int KK = 20;      // neighbors
constexpr int NPT = BB*NN;  // total points 16384
constexpr float EPSF = 1e-5f;
constexpr float NEGINF = -3.0e38f;

DI float lrelu(float x){ return x >= 0.f ? x : 0.2f * x; }
DI float dot4(const float4 a, const float4 b){ return a.x*b.x + a.y*b.y + a.z*b.z + a.w*b.w; }
DI unsigned short f2bf(float x){            // round-to-nearest-even bf16
    uint32_t u = __float_as_uint(x);
    uint32_t r = (u + 0x7fffu + ((u >> 16) & 1u)) >> 16;
    return (unsigned short)r;
}

typedef __attribute__((ext_vector_type(8))) short short8v;  // bf16x8 MFMA fragment
typedef __attribute__((ext_vector_type(4))) float f32x4;

// ---------------------------------------------------------------- transpose x [B,3,N] -> xt0 [B,N,3]
__global__ void k_transpose(const float* __restrict__ x, float* __restrict__ xt)
{
    int i = blockIdx.x * 256 + threadIdx.x;
    if (i >= NPT) return;
    int b = i >> 10, n = i & 1023;
    #pragma unroll
    for (int c = 0; c < 3; ++c) xt[i*3 + c] = x[(b*3 + c)*NN + n];
}

// ---------------------------------------------------------------- squared norms per point
__global__ void k_sqnorm(const float* __restrict__ src, int stride, int C, float* __restrict__ xx)
{
    int i = blockIdx.x * 256 + threadIdx.x;
    if (i >= NPT) return;
    const float* r = src + (size_t)i * stride;
    float s = 0.f;
    for (int c = 0; c < C; ++c){ float v = r[c]; s += v * v; }
    xx[i] = s;
}

// ---------------------------------------------------------------- kNN
// Block = 1024 threads (16 waves), 64 queries (wave -> 4 queries), grid 256
// (1 block/CU). Candidates tiled 128 at a time into XOR-swizzled LDS (full
// coalesced rows). Queries: wave-uniform GLOBAL loads (scalar/L1 broadcast,
// off the LDS pipe) — R6's qbuf LDS re-reads were 2/3 of the LDS traffic.
// Selection: per-lane bitonic sort + 21-round tournament + set emission.
template<int C>
__global__ __launch_bounds__(1024, 4) void k_knn(const float* __restrict__ src, int stride,
                                                 const float* __restrict__ xx,
                                                 int* __restrict__ idxo)
{
    constexpr bool SMALL = (C == 3);
    constexpr int CG = SMALL ? 1 : (C / 4);
    constexpr int TS = SMALL ? 5 : C;
    __shared__ float tile[128 * TS];

    const int tid  = threadIdx.x;
    const int lane = tid & 63;
    const int wv   = __builtin_amdgcn_readfirstlane(tid >> 6);  // 0..15 uniform
    const int b  = blockIdx.x >> 4;
    const int q0 = (blockIdx.x & 15) << 6;
    const int qbase = b*NN + q0 + (wv << 2);      // wave's first query (uniform)

    // uniform query-row pointers (scalar loads, L1-resident after tile 0)
    const float* qp0 = src + (size_t)(qbase + 0)*stride;
    const float* qp1 = src + (size_t)(qbase + 1)*stride;
    const float* qp2 = src + (size_t)(qbase + 2)*stride;
    const float* qp3 = src + (size_t)(qbase + 3)*stride;

    float xxq[4];
    #pragma unroll
    for (int q = 0; q < 4; ++q) xxq[q] = xx[qbase + q];

    float val[4][16];

    #pragma unroll
    for (int t = 0; t < 8; ++t){
        __syncthreads();
        // ---- stage candidate tile t (full rows, coalesced) ----
        if constexpr (SMALL){
            for (int i = tid; i < 128*3; i += 1024){
                int row = i / 3, c = i % 3;
                tile[row*TS + c] = src[(size_t)(b*NN + t*128 + row)*stride + c];
            }
        } else {
            for (int i = tid; i < 128*CG; i += 1024){
                int row = i / CG, cg = i % CG;
                int p = cg ^ (row & (CG - 1));    // XOR swizzle
                float4 v = *(const float4*)(src + (size_t)(b*NN + t*128 + row)*stride + cg*4);
                *(float4*)(tile + row*TS + p*4) = v;
            }
        }
        __syncthreads();

        float acc[4][2];
        #pragma unroll
        for (int q = 0; q < 4; ++q){ acc[q][0] = 0.f; acc[q][1] = 0.f; }

        if constexpr (SMALL){
            float c0a = tile[lane*TS+0], c0b = tile[lane*TS+1], c0c = tile[lane*TS+2];
            float c1a = tile[(64+lane)*TS+0], c1b = tile[(64+lane)*TS+1], c1c = tile[(64+lane)*TS+2];
            float q00 = qp0[0], q01 = qp0[1], q02 = qp0[2];
            float q10 = qp1[0], q11 = qp1[1], q12 = qp1[2];
            float q20 = qp2[0], q21 = qp2[1], q22 = qp2[2];
            float q30 = qp3[0], q31 = qp3[1], q32 = qp3[2];
            acc[0][0] = q00*c0a + q01*c0b + q02*c0c;  acc[0][1] = q00*c1a + q01*c1b + q02*c1c;
            acc[1][0] = q10*c0a + q11*c0b + q12*c0c;  acc[1][1] = q10*c1a + q11*c1b + q12*c1c;
            acc[2][0] = q20*c0a + q21*c0b + q22*c0c;  acc[2][1] = q20*c1a + q21*c1b + q22*c1c;
            acc[3][0] = q30*c0a + q31*c0b + q32*c0c;  acc[3][1] = q30*c1a + q31*c1b + q32*c1c;
        } else {
            const int sw = lane & (CG - 1);
            #pragma unroll 2
            for (int cg0 = 0; cg0 < CG; ++cg0){
                float4 cf0 = *(const float4*)(tile + lane*TS      + ((cg0 ^ sw) << 2));
                float4 cf1 = *(const float4*)(tile + (64+lane)*TS + ((cg0 ^ sw) << 2));
                float4 qf0 = *(const float4*)(qp0 + (cg0 << 2));
                float4 qf1 = *(const float4*)(qp1 + (cg0 << 2));
                float4 qf2 = *(const float4*)(qp2 + (cg0 << 2));
                float4 qf3 = *(const float4*)(qp3 + (cg0 << 2));
                acc[0][0] += dot4(qf0, cf0); acc[0][1] += dot4(qf0, cf1);
                acc[1][0] += dot4(qf1, cf0); acc[1][1] += dot4(qf1, cf1);
                acc[2][0] += dot4(qf2, cf0); acc[2][1] += dot4(qf2, cf1);
                acc[3][0] += dot4(qf3, cf0); acc[3][1] += dot4(qf3, cf1);
            }
        }
        float xxm0 = xx[b*NN + t*128 + lane];
        float xxm1 = xx[b*NN + t*128 + 64 + lane];
        #pragma unroll
        for (int q = 0; q < 4; ++q){
            val[q][2*t]   = 2.f*acc[q][0] - xxq[q] - xxm0;
            val[q][2*t+1] = 2.f*acc[q][1] - xxq[q] - xxm1;
        }
    }

    // ---- selection per query ----
    #pragma unroll
    for (int q = 0; q < 4; ++q){
        const int orow = (qbase + q) * KK;

        // copy + bitonic sort descending (values only, static indices)
        float s[16];
        #pragma unroll
        for (int j = 0; j < 16; ++j) s[j] = val[q][j];
        #pragma unroll
        for (int k = 2; k <= 16; k <<= 1){
            #pragma unroll
            for (int jj = k >> 1; jj > 0; jj >>= 1){
                #pragma unroll
                for (int i = 0; i < 16; ++i){
                    int l = i ^ jj;
                    if (l > i){
                        float a = s[i], c = s[l];
                        float mx = fmaxf(a, c), mn = fminf(a, c);
                        bool up = ((i & k) == 0);
                        s[i] = up ? mx : mn;
                        s[l] = up ? mn : mx;
                    }
                }
            }
        }

        // 21 tournament rounds over lane heads -> T = 21st-largest
        float T = NEGINF;
        for (int it = 0; it < 21; ++it){
            float m = s[0];
            #pragma unroll
            for (int d = 1; d < 64; d <<= 1) m = fmaxf(m, __shfl_xor(m, d));
            T = m;
            unsigned long long mk = __ballot(s[0] == m);
            int wl = __ffsll(mk) - 1;
            bool adv = (lane == wl);
            #pragma unroll
            for (int j = 0; j < 15; ++j) s[j] = adv ? s[j+1] : s[j];
            s[15] = adv ? NEGINF : s[15];
        }

        // emit {val > T} (order irrelevant downstream), fill ==T by lowest index
        int cnt = 0;
        #pragma unroll
        for (int j = 0; j < 16; ++j) cnt += (val[q][j] > T) ? 1 : 0;
        int off = cnt;
        #pragma unroll
        for (int d = 1; d < 64; d <<= 1){
            int tt = __shfl_up(off, d);
            if (lane >= d) off += tt;
        }
        int total = __shfl(off, 63);
        int pos = orow + off - cnt;
        #pragma unroll
        for (int j = 0; j < 16; ++j){
            if (val[q][j] > T){ idxo[pos] = j*64 + lane; ++pos; }
        }
        if (total < KK){
            int rem = KK - total;
            int prior = 0;
            #pragma unroll
            for (int j = 0; j < 16; ++j){
                unsigned long long mk = __ballot(val[q][j] == T);
                int below = __popcll(mk & ((1ull << lane) - 1ull));
                if ((val[q][j] == T) && (prior + below < rem))
                    idxo[orow + total + prior + below] = j*64 + lane;
                prior += __popcll(mk);
            }
        }
    }
}

// ---------------------------------------------------------------- weight prep: W' = [Wj ; Wi-Wj]
__global__ void k_wprep(const float* __restrict__ w, int O, int C, float* __restrict__ wp)
{
    int i = blockIdx.x*256 + threadIdx.x;
    if (i >= O*C) return;
    int o = i / C, c = i % C;
    float a = w[o*2*C + c];
    float bq = w[o*2*C + C + c];
    wp[o*C + c]       = a;
    wp[(O + o)*C + c] = bq - a;
}

// ---------------------------------------------------------------- u/v GEMM (fp32: feeds next kNN, must stay exact)
template<int K, int M2, int O>
__global__ __launch_bounds__(256) void k_uvgemm(const float* __restrict__ srcp,
    const float* __restrict__ wp,
    const float* __restrict__ g, const float* __restrict__ bp,
    const float* __restrict__ mp, const float* __restrict__ vp,
    float* __restrict__ ub, float* __restrict__ xcv)
{
    constexpr int LD = 136;
    __shared__ float wl[16*LD];
    __shared__ float xl[16*LD];
    const int tid = threadIdx.x;
    const int nt = blockIdx.x & 127;
    const int mt = blockIdx.x >> 7;
    const int to = tid >> 4, tn = tid & 15;

    float acc[8][8];
    #pragma unroll
    for (int i = 0; i < 8; ++i)
        #pragma unroll
        for (int j = 0; j < 8; ++j) acc[i][j] = 0.f;

    for (int c0 = 0; c0 < K; c0 += 16){
        __syncthreads();
        #pragma unroll
        for (int p = 0; p < 2; ++p){
            int fi = tid + (p << 8);
            int row = fi >> 2, cq = (fi & 3) << 2;
            float4 wv = *(const float4*)(wp + (size_t)(mt*128 + row)*K + c0 + cq);
            wl[(cq+0)*LD + row] = wv.x;
            wl[(cq+1)*LD + row] = wv.y;
            wl[(cq+2)*LD + row] = wv.z;
            wl[(cq+3)*LD + row] = wv.w;
            float4 xv = *(const float4*)(srcp + (size_t)(nt*128 + row)*512 + c0 + cq);
            xl[(cq+0)*LD + row] = xv.x;
            xl[(cq+1)*LD + row] = xv.y;
            xl[(cq+2)*LD + row] = xv.z;
            xl[(cq+3)*LD + row] = xv.w;
        }
        __syncthreads();
        #pragma unroll
        for (int cc = 0; cc < 16; ++cc){
            float4 a0 = *(const float4*)(wl + cc*LD + to*8);
            float4 a1 = *(const float4*)(wl + cc*LD + to*8 + 4);
            float4 b0 = *(const float4*)(xl + cc*LD + tn*8);
            float4 b1 = *(const float4*)(xl + cc*LD + tn*8 + 4);
            float av[8] = {a0.x,a0.y,a0.z,a0.w,a1.x,a1.y,a1.z,a1.w};
            float bv[8] = {b0.x,b0.y,b0.z,b0.w,b1.x,b1.y,b1.z,b1.w};
            #pragma unroll
            for (int i = 0; i < 8; ++i)
                #pragma unroll
                for (int j = 0; j < 8; ++j) acc[i][j] += av[i]*bv[j];
        }
    }

    const int mbase = mt*128 + to*8;
    const bool isu = mbase < O;
    float mult[8], add[8];
    #pragma unroll
    for (int i = 0; i < 8; ++i){
        int m = mbase + i;
        if (isu){
            float s = g[m] / sqrtf(vp[m] + EPSF);
            mult[i] = (s >= 0.f) ? 1.f : -1.f;
            add[i]  = 0.f;
        } else {
            int o = m - O;
            float s = g[o] / sqrtf(vp[o] + EPSF);
            mult[i] = s;
            add[i]  = bp[o] - mp[o]*s;
        }
    }
    #pragma unroll
    for (int j = 0; j < 8; ++j){
        int pt = nt*128 + tn*8 + j;
        float4 v0, v1;
        v0.x = fmaf(mult[0], acc[0][j], add[0]);
        v0.y = fmaf(mult[1], acc[1][j], add[1]);
        v0.z = fmaf(mult[2], acc[2][j], add[2]);
        v0.w = fmaf(mult[3], acc[3][j], add[3]);
        v1.x = fmaf(mult[4], acc[4][j], add[4]);
        v1.y = fmaf(mult[5], acc[5][j], add[5]);
        v1.z = fmaf(mult[6], acc[6][j], add[6]);
        v1.w = fmaf(mult[7], acc[7][j], add[7]);
        if (isu){
            float* d = ub + (size_t)pt*O + mbase;
            *(float4*)(d)     = v0;
            *(float4*)(d + 4) = v1;
        } else {
            float* d = xcv + (size_t)pt*512 + (mbase - O);
            *(float4*)(d)     = v0;
            *(float4*)(d + 4) = v1;
        }
    }
}

// ---------------------------------------------------------------- layer-1 u/v (C=3) direct
__global__ __launch_bounds__(256) void k_uv3(const float* __restrict__ xt,
    const float* __restrict__ wp,
    const float* __restrict__ g, const float* __restrict__ bp,
    const float* __restrict__ mp, const float* __restrict__ vp,
    float* __restrict__ ub, float* __restrict__ xcv)
{
    __shared__ float wpl[128*3];
    __shared__ float mult[128], add[128];
    const int tid = threadIdx.x;
    if (tid < 128){
        int m = tid;
        if (m < 64){
            float s = g[m] / sqrtf(vp[m] + EPSF);
            mult[m] = (s >= 0.f) ? 1.f : -1.f;
            add[m]  = 0.f;
        } else {
            int o = m - 64;
            float s = g[o] / sqrtf(vp[o] + EPSF);
            mult[m] = s;
            add[m]  = bp[o] - mp[o]*s;
        }
    }
    for (int i = tid; i < 128*3; i += 256) wpl[i] = wp[i];
    __syncthreads();

    const int ptl = tid >> 5, mg = tid & 31;
    const int m0 = mg * 4;
    const int pt = blockIdx.x*8 + ptl;
    float x0 = xt[pt*3+0], x1 = xt[pt*3+1], x2 = xt[pt*3+2];
    float4 v4;
    float tmp[4];
    #pragma unroll
    for (int r = 0; r < 4; ++r){
        int m = m0 + r;
        float a = wpl[m*3+0]*x0 + wpl[m*3+1]*x1 + wpl[m*3+2]*x2;
        tmp[r] = fmaf(mult[m], a, add[m]);
    }
    v4.x = tmp[0]; v4.y = tmp[1]; v4.z = tmp[2]; v4.w = tmp[3];
    if (m0 < 64) *(float4*)(ub + (size_t)pt*64 + m0) = v4;
    else         *(float4*)(xcv + (size_t)pt*512 + (m0 - 64)) = v4;
}

// ---------------------------------------------------------------- combine: out = lrelu(|s| * max_k u'[j_k] + v')
template<int O>
__global__ __launch_bounds__(256) void k_edgemax(const float* __restrict__ ub,
    const int* __restrict__ idxg,
    const float* __restrict__ g, const float* __restrict__ vp,
    float* __restrict__ xcv)
{
    constexpr int TPP = O / 4;
    constexpr int PPB = 256 / TPP;
    const int tid = threadIdx.x;
    const int pt  = blockIdx.x*PPB + tid / TPP;
    const int oq  = (tid % TPP) * 4;
    const int bb  = pt & ~(NN-1);

    int nb[KK];
    #pragma unroll
    for (int k = 0; k < KK; ++k) nb[k] = idxg[pt*KK + k];

    float4 mx = *(const float4*)(ub + (size_t)(bb + nb[0])*O + oq);
    #pragma unroll
    for (int k = 1; k < KK; ++k){
        float4 u = *(const float4*)(ub + (size_t)(bb + nb[k])*O + oq);
        mx.x = fmaxf(mx.x, u.x); mx.y = fmaxf(mx.y, u.y);
        mx.z = fmaxf(mx.z, u.z); mx.w = fmaxf(mx.w, u.w);
    }
    float4 gv = *(const float4*)(g + oq);
    float4 vv = *(const float4*)(vp + oq);
    float4 as;
    as.x = fabsf(gv.x / sqrtf(vv.x + EPSF));
    as.y = fabsf(gv.y / sqrtf(vv.y + EPSF));
    as.z = fabsf(gv.z / sqrtf(vv.z + EPSF));
    as.w = fabsf(gv.w / sqrtf(vv.w + EPSF));
    float* d = xcv + (size_t)pt*512 + oq;
    float4 vr = *(const float4*)(d);
    float4 y;
    y.x = lrelu(fmaf(as.x, mx.x, vr.x));
    y.y = lrelu(fmaf(as.y, mx.y, vr.y));
    y.z = lrelu(fmaf(as.z, mx.z, vr.z));
    y.w = lrelu(fmaf(as.w, mx.w, vr.w));
    *(float4*)(d) = y;
}

// ---------------------------------------------------------------- fp32 -> bf16 cast (8 elems/thread)
__global__ void k_castbf(const float* __restrict__ s, unsigned short* __restrict__ d, int n8)
{
    int i = blockIdx.x*256 + threadIdx.x;
    if (i >= n8) return;
    const float4* sp = (const float4*)s + (size_t)i*2;
    float4 a = sp[0], b = sp[1];
    union { unsigned short u[8]; uint4 v; } o;
    o.u[0] = f2bf(a.x); o.u[1] = f2bf(a.y); o.u[2] = f2bf(a.z); o.u[3] = f2bf(a.w);
    o.u[4] = f2bf(b.x); o.u[5] = f2bf(b.y); o.u[6] = f2bf(b.z); o.u[7] = f2bf(b.w);
    *((uint4*)d + i) = o.v;
}

// ---------------------------------------------------------------- conv5 bf16 MFMA GEMM + BN + LReLU + pool partials
__global__ __launch_bounds__(256) void k_conv5mfma(const unsigned short* __restrict__ xcb,
    const unsigned short* __restrict__ w5b,
    const float* __restrict__ g, const float* __restrict__ bp,
    const float* __restrict__ mp, const float* __restrict__ vp,
    float* __restrict__ pmax, float* __restrict__ psum)
{
    __shared__ __align__(16) short lA[128*32];
    __shared__ __align__(16) short lB[128*32];
    __shared__ float scl[128], adl[128];
    __shared__ float red[2][128][2];

    const int tid = threadIdx.x;
    const int lane = tid & 63, wave = tid >> 6;
    const int wm = wave >> 1, wn = wave & 1;
    const int b  = blockIdx.x >> 6;
    const int mt = (blockIdx.x >> 3) & 7;
    const int nt = blockIdx.x & 7;

    if (tid < 128){
        int o = mt*128 + tid;
        float s = g[o] / sqrtf(vp[o] + EPSF);
        scl[tid] = s;
        adl[tid] = bp[o] - mp[o]*s;
    }

    f32x4 acc[4][4];
    #pragma unroll
    for (int i = 0; i < 4; ++i)
        #pragma unroll
        for (int j = 0; j < 4; ++j) acc[i][j] = (f32x4){0.f,0.f,0.f,0.f};

    const unsigned short* gA = w5b + (size_t)(mt*128)*512;
    const unsigned short* gB = xcb + (size_t)(b*1024 + nt*128)*512;

    for (int ks = 0; ks < 16; ++ks){
        __syncthreads();
        #pragma unroll
        for (int p = 0; p < 2; ++p){
            int off = p*256 + tid;
            int row = off >> 2;
            int slot = off & 3;
            int ssl = slot ^ (row & 3);
            *(uint4*)(lA + row*32 + ssl*8) = *(const uint4*)(gA + (size_t)row*512 + ks*32 + slot*8);
            *(uint4*)(lB + row*32 + ssl*8) = *(const uint4*)(gB + (size_t)row*512 + ks*32 + slot*8);
        }
        __syncthreads();

        short8v afr[4], bfr[4];
        #pragma unroll
        for (int i = 0; i < 4; ++i){
            int row = wm*64 + i*16 + (lane & 15);
            int sl  = (lane >> 4) ^ (row & 3);
            afr[i] = *(const short8v*)(lA + row*32 + sl*8);
        }
        #pragma unroll
        for (int j = 0; j < 4; ++j){
            int row = wn*64 + j*16 + (lane & 15);
            int sl  = (lane >> 4) ^ (row & 3);
            bfr[j] = *(const short8v*)(lB + row*32 + sl*8);
        }
        #pragma unroll
        for (int i = 0; i < 4; ++i)
            #pragma unroll
            for (int j = 0; j < 4; ++j)
                acc[i][j] = __builtin_amdgcn_mfma_f32_16x16x32_bf16(afr[i], bfr[j], acc[i][j], 0, 0, 0);
    }

    float emx[4][4], esm[4][4];
    #pragma unroll
    for (int i = 0; i < 4; ++i){
        #pragma unroll
        for (int r = 0; r < 4; ++r){
            int m_loc = wm*64 + i*16 + (lane >> 4)*4 + r;
            float s = scl[m_loc], t = adl[m_loc];
            float mx = NEGINF, sm = 0.f;
            #pragma unroll
            for (int j = 0; j < 4; ++j){
                float y = lrelu(fmaf(acc[i][j][r], s, t));
                mx = fmaxf(mx, y); sm += y;
            }
            #pragma unroll
            for (int d = 1; d < 16; d <<= 1){
                mx = fmaxf(mx, __shfl_xor(mx, d));
                sm += __shfl_xor(sm, d);
            }
            emx[i][r] = mx; esm[i][r] = sm;
        }
    }
    if ((lane & 15) == 0){
        #pragma unroll
        for (int i = 0; i < 4; ++i)
            #pragma unroll
            for (int r = 0; r < 4; ++r){
                int m_loc = wm*64 + i*16 + (lane >> 4)*4 + r;
                red[wn][m_loc][0] = emx[i][r];
                red[wn][m_loc][1] = esm[i][r];
            }
    }
    __syncthreads();
    if (tid < 128){
        float mx = fmaxf(red[0][tid][0], red[1][tid][0]);
        float sm = red[0][tid][1] + red[1][tid][1];
        int o = mt*128 + tid;
        pmax[(size_t)(b*NN + o)*8 + nt] = mx;
        psum[(size_t)(b*NN + o)*8 + nt] = sm;
    }
}

__global__ void k_poolfin(const float* __restrict__ pmax, const float* __restrict__ psum,
                          float* __restrict__ p)
{
    int i = blockIdx.x*256 + threadIdx.x;
    if (i >= NPT) return;
    int b = i >> 10, o = i & 1023;
    float mx = NEGINF, sm = 0.f;
    #pragma unroll
    for (int t = 0; t < 8; ++t){ mx = fmaxf(mx, pmax[(size_t)i*8 + t]); sm += psum[(size_t)i*8 + t]; }
    p[b*2048 + o]        = mx;
    p[b*2048 + 1024 + o] = sm * (1.f/1024.f);
}

// ---------------------------------------------------------------- small FC layers
template<int IN, int O, bool HASBN, bool HASBIAS>
__global__ void k_fc(const float* __restrict__ in, const float* __restrict__ W,
                     const float* __restrict__ bias,
                     const float* __restrict__ g, const float* __restrict__ bp,
                     const float* __restrict__ mp, const float* __restrict__ vp,
                     float* __restrict__ out)
{
    int i = blockIdx.x*256 + threadIdx.x;
    if (i >= BB*O) return;
    int b = i / O, o = i % O;
    const float* wr = W  + (size_t)o*IN;
    const float* ir = in + (size_t)b*IN;
    float s = 0.f;
    #pragma unroll 4
    for (int c = 0; c < IN; c += 4){
        float4 a = *(const float4*)(wr + c);
        float4 x = *(const float4*)(ir + c);
        s += dot4(a, x);
    }
    if (HASBIAS) s += bias[o];
    if (HASBN){
        float sc = g[o] / sqrtf(vp[o] + EPSF);
        s = (s - mp[o])*sc + bp[o];
        s = lrelu(s);
    }
    out[(size_t)b*O + o] = s;
}

// ---------------------------------------------------------------- launch
extern "C" void kernel_launch(void* const* d_in, const int* in_sizes, int n_in,
                              void* d_out, int out_size, void* d_ws, size_t ws_size,
                              hipStream_t stream)
{
    (void)in_sizes; (void)n_in; (void)out_size; (void)ws_size;
    const float* x   = (const float*)d_in[0];
    const float* w1  = (const float*)d_in[1];
    const float* w2  = (const float*)d_in[2];
    const float* w3  = (const float*)d_in[3];
    const float* w4  = (const float*)d_in[4];
    const float* w5  = (const float*)d_in[5];
    const float* wl1 = (const float*)d_in[6];
    const float* wl2 = (const float*)d_in[7];
    const float* wl3 = (const float*)d_in[8];
    const float* bl2 = (const float*)d_in[9];
    const float* bl3 = (const float*)d_in[10];
    const float* g1 = (const float*)d_in[11]; const float* b1 = (const float*)d_in[12];
    const float* m1 = (const float*)d_in[13]; const float* v1 = (const float*)d_in[14];
    const float* g2 = (const float*)d_in[15]; const float* b2 = (const float*)d_in[16];
    const float* m2 = (const float*)d_in[17]; const float* v2 = (const float*)d_in[18];
    const float* g3 = (const float*)d_in[19]; const float* b3 = (const float*)d_in[20];
    const float* m3 = (const float*)d_in[21]; const float* v3 = (const float*)d_in[22];
    const float* g4 = (const float*)d_in[23]; const float* b4 = (const float*)d_in[24];
    const float* m4 = (const float*)d_in[25]; const float* v4 = (const float*)d_in[26];
    const float* g5 = (const float*)d_in[27]; const float* b5 = (const float*)d_in[28];
    const float* m5 = (const float*)d_in[29]; const float* v5 = (const float*)d_in[30];
    const float* g6 = (const float*)d_in[31]; const float* b6 = (const float*)d_in[32];
    const float* m6 = (const float*)d_in[33]; const float* v6 = (const float*)d_in[34];
    const float* g7 = (const float*)d_in[35]; const float* b7 = (const float*)d_in[36];
    const float* m7 = (const float*)d_in[37]; const float* v7 = (const float*)d_in[38];

    float* wsf  = (float*)d_ws;
    float* xt0  = wsf;                    // 49152
    float* xc   = xt0 + 49152;            // 8388608
    float* xx   = xc + 8388608;           // 16384
    int*   idx  = (int*)(xx + 16384);     // 327680 ints
    float* pmax = (float*)(idx + 327680); // 131072
    float* psum = pmax + 131072;          // 131072
    float* p    = psum + 131072;          // 32768
    float* h1   = p + 32768;              // 8192
    float* h2   = h1 + 8192;              // 4096
    float* ub   = h2 + 4096;              // 4194304
    float* wp   = ub + 4194304;           // 65536
    unsigned short* xcb = (unsigned short*)ub;   // bf16 alias (ub dead by conv5)
    unsigned short* w5b = (unsigned short*)idx;  // bf16 alias (idx dead by conv5)

    k_transpose<<<64, 256, 0, stream>>>(x, xt0);

    // block 1: C=3 -> O=64 (channels 0..63)
    k_sqnorm<<<64, 256, 0, stream>>>(xt0, 3, 3, xx);
    k_knn<3><<<256, 1024, 0, stream>>>(xt0, 3, xx, idx);
    k_wprep<<<1, 256, 0, stream>>>(w1, 64, 3, wp);
    k_uv3<<<2048, 256, 0, stream>>>(xt0, wp, g1, b1, m1, v1, ub, xc);
    k_edgemax<64><<<1024, 256, 0, stream>>>(ub, idx, g1, v1, xc);

    // block 2: C=64 -> O=64 (channels 64..127)
    k_sqnorm<<<64, 256, 0, stream>>>(xc, 512, 64, xx);
    k_knn<64><<<256, 1024, 0, stream>>>(xc, 512, xx, idx);
    k_wprep<<<16, 256, 0, stream>>>(w2, 64, 64, wp);
    k_uvgemm<64, 128, 64><<<128, 256, 0, stream>>>(xc, wp, g2, b2, m2, v2, ub, xc + 64);
    k_edgemax<64><<<1024, 256, 0, stream>>>(ub, idx, g2, v2, xc + 64);

    // block 3: C=64 -> O=128 (channels 128..255)
    k_sqnorm<<<64, 256, 0, stream>>>(xc + 64, 512, 64, xx);
    k_knn<64><<<256, 1024, 0, stream>>>(xc + 64, 512, xx, idx);
    k_wprep<<<32, 256, 0, stream>>>(w3, 128, 64, wp);
    k_uvgemm<64, 256, 128><<<256, 256, 0, stream>>>(xc + 64, wp, g3, b3, m3, v3, ub, xc + 128);
    k_edgemax<128><<<2048, 256, 0, stream>>>(ub, idx, g3, v3, xc + 128);

    // block 4: C=128 -> O=256 (channels 256..511)
    k_sqnorm<<<64, 256, 0, stream>>>(xc + 128, 512, 128, xx);
    k_knn<128><<<256, 1024, 0, stream>>>(xc + 128, 512, xx, idx);
    k_wprep<<<128, 256, 0, stream>>>(w4, 256, 128, wp);
    k_uvgemm<128, 512, 256><<<512, 256, 0, stream>>>(xc + 128, wp, g4, b4, m4, v4, ub, xc + 256);
    k_edgemax<256><<<4096, 256, 0, stream>>>(ub, idx, g4, v4, xc + 256);

    // conv5: cast to bf16 (ub/idx now dead), MFMA GEMM + fused BN/LReLU/pool
    k_castbf<<<4096, 256, 0, stream>>>(xc, xcb, 1048576);
    k_castbf<<<256, 256, 0, stream>>>(w5, w5b, 65536);
    k_conv5mfma<<<1024, 256, 0, stream>>>(xcb, w5b, g5, b5, m5, v5, pmax, psum);
    k_poolfin<<<64, 256, 0, stream>>>(pmax, psum, p);

    // FC head
    k_fc<2048, 512, true,  false><<<32, 256, 0, stream>>>(p,  wl1, nullptr, g6, b6, m6, v6, h1);
    k_fc<512,  256, true,  true ><<<16, 256, 0, stream>>>(h1, wl2, bl2,     g7, b7, m7, v7, h2);
    k_fc<256,  101, false, true ><<<7,  256, 0, stream>>>(h2, wl3, bl3, nullptr, nullptr, nullptr, nullptr, (float*)d_out);
}